// Round 2
// baseline (533.364 us; speedup 1.0000x reference)
//
#include <hip/hip_runtime.h>
#include <hip/hip_bf16.h>
#include <stdint.h>
#include <stddef.h>

#define NB 2
#define SEQ 2048
#define HIDN 1024
#define NHEAD 16
#define HDIM 64
#define MTOT (NB * SEQ)   // 4096

typedef short bf16x8 __attribute__((ext_vector_type(8)));
typedef float f32x4 __attribute__((ext_vector_type(4)));

#define MFMA16(a, b, c) __builtin_amdgcn_mfma_f32_16x16x32_bf16(a, b, c, 0, 0, 0)

__device__ __forceinline__ unsigned short f2bf(float f) {
  union { float f; uint32_t u; } v; v.f = f;
  uint32_t u = v.u;
  uint32_t r = (u + 0x7fffu + ((u >> 16) & 1u)) >> 16;
  return (unsigned short)r;
}

__device__ __forceinline__ short bfc(float f) {
  __hip_bfloat16 h = __float2bfloat16(f);
  return *reinterpret_cast<short*>(&h);
}

__device__ __forceinline__ void gload16(const void* g, void* l) {
  __builtin_amdgcn_global_load_lds((const __attribute__((address_space(1))) void*)g,
                                   (__attribute__((address_space(3))) void*)l,
                                   16, 0, 0);
}

// ---------------- kernel 1: fp32 -> bf16 conversion ----------------
__global__ void cvt_bf16(const float* __restrict__ x, const float* __restrict__ wq,
                         const float* __restrict__ wk, const float* __restrict__ wv,
                         unsigned short* __restrict__ dst)
{
  size_t i4 = ((size_t)blockIdx.x * blockDim.x + threadIdx.x) * 4;
  const float* s; size_t off;
  if (i4 < 4194304UL)      { s = x;  off = i4; }
  else if (i4 < 5242880UL) { s = wq; off = i4 - 4194304UL; }
  else if (i4 < 6291456UL) { s = wk; off = i4 - 5242880UL; }
  else                     { s = wv; off = i4 - 6291456UL; }
  float4 v = *(const float4*)(s + off);
  ushort4 o;
  o.x = f2bf(v.x); o.y = f2bf(v.y); o.z = f2bf(v.z); o.w = f2bf(v.w);
  *(ushort4*)(dst + i4) = o;
}

// ---------------- kernel 2: QKV projection GEMM (NT, bf16 MFMA) ----------------
// C[i,j] = sum_k xb[i,k] * W[j,k]; z: {wq->Qb, wk->Kb (row-permuted), wv->Vt (transposed)}
// Kb row permutation (within each 32-token group), so that in the attention
// kernel's swapped QK^T each lane ends up holding 8 CONSECUTIVE actual keys:
//   storage_row(m) = (m & ~31) | (((m>>2)&1)<<4) | (((m>>3)&3)<<2) | (m&3)
__global__ __launch_bounds__(256, 2) void qkv_gemm(
    const unsigned short* __restrict__ xb,
    const unsigned short* __restrict__ wqb,
    const unsigned short* __restrict__ wkb,
    const unsigned short* __restrict__ wvb,
    unsigned short* __restrict__ Qb,
    unsigned short* __restrict__ Kb,
    unsigned short* __restrict__ Vt)
{
  __shared__ unsigned short As[128 * 64];
  __shared__ unsigned short Bs[128 * 64];

  const int z = blockIdx.z;
  const unsigned short* W = (z == 0) ? wqb : (z == 1) ? wkb : wvb;
  const int n0 = blockIdx.x * 128;
  const int m0 = blockIdx.y * 128;
  const int tid = threadIdx.x;
  const int lane = tid & 63;
  const int wid = tid >> 6;
  const int l15 = lane & 15;
  const int lg = lane >> 4;

  f32x4 acc[4][4] = {};

  const int wr = (wid >> 1) * 64;
  const int wc = (wid & 1) * 64;

  for (int kt = 0; kt < 16; ++kt) {
    __syncthreads();
    #pragma unroll
    for (int i = 0; i < 4; ++i) {
      int row = wid * 32 + i * 8 + (lane >> 3);
      int chunk = (lane & 7) ^ (row & 7);
      const unsigned short* ga = xb + (size_t)(m0 + row) * HIDN + kt * 64 + chunk * 8;
      const unsigned short* gb = W  + (size_t)(n0 + row) * HIDN + kt * 64 + chunk * 8;
      gload16(ga, (char*)As + wid * 4096 + i * 1024);
      gload16(gb, (char*)Bs + wid * 4096 + i * 1024);
    }
    __syncthreads();

    #pragma unroll
    for (int ks = 0; ks < 2; ++ks) {
      bf16x8 af[4], bfr[4];
      #pragma unroll
      for (int mi = 0; mi < 4; ++mi) {
        int row = wr + mi * 16 + l15;
        int cb = (ks * 64 + lg * 16) ^ ((row & 7) << 4);
        af[mi] = *(const bf16x8*)((const char*)As + row * 128 + cb);
      }
      #pragma unroll
      for (int ni = 0; ni < 4; ++ni) {
        int row = wc + ni * 16 + l15;
        int cb = (ks * 64 + lg * 16) ^ ((row & 7) << 4);
        bfr[ni] = *(const bf16x8*)((const char*)Bs + row * 128 + cb);
      }
      #pragma unroll
      for (int mi = 0; mi < 4; ++mi)
        #pragma unroll
        for (int ni = 0; ni < 4; ++ni)
          acc[mi][ni] = MFMA16(af[mi], bfr[ni], acc[mi][ni]);
    }
  }

  if (z < 2) {
    unsigned short* O = (z == 0) ? Qb : Kb;
    #pragma unroll
    for (int mi = 0; mi < 4; ++mi)
      #pragma unroll
      for (int ni = 0; ni < 4; ++ni) {
        int n = n0 + wc + ni * 16 + l15;
        #pragma unroll
        for (int e = 0; e < 4; ++e) {
          int m = m0 + wr + mi * 16 + lg * 4 + e;
          int mm = m;
          if (z == 1)
            mm = (m & ~31) | (((m >> 2) & 1) << 4) | (((m >> 3) & 3) << 2) | (m & 3);
          O[(size_t)mm * HIDN + n] = f2bf(acc[mi][ni][e]);
        }
      }
  } else {
    #pragma unroll
    for (int mi = 0; mi < 4; ++mi)
      #pragma unroll
      for (int ni = 0; ni < 4; ++ni) {
        int n = n0 + wc + ni * 16 + l15;
        int m = m0 + wr + mi * 16 + lg * 4;
        ushort4 pk;
        pk.x = f2bf(acc[mi][ni][0]);
        pk.y = f2bf(acc[mi][ni][1]);
        pk.z = f2bf(acc[mi][ni][2]);
        pk.w = f2bf(acc[mi][ni][3]);
        *(ushort4*)(Vt + (size_t)n * MTOT + m) = pk;
      }
  }
}

// ---------------- kernel 3: attention, fully independent waves ----------------
// Each wave: 16 q-rows x all 2048 keys. Two passes (stats, then emit).
// Swapped QK^T: mfma(A=K, B=Q) -> lane holds (q = lane&15, keys per K-permutation).
// No LDS, no __syncthreads. Score stored as dwordx4; P feeds PV from registers.
__global__ __launch_bounds__(128) void attn2(
    const unsigned short* __restrict__ Qb,
    const unsigned short* __restrict__ Kb,
    const unsigned short* __restrict__ Vt,
    float* __restrict__ out)
{
  const int bid = blockIdx.x;            // 0..2047
  const int xcd = bid & 7;
  const int k7 = bid >> 3;               // 0..255
  const int qg = k7 & 63;                // 0..63
  const int ps = k7 >> 6;                // 0..3
  const int pan = ps * 8 + xcd;          // panel 0..31 -> XCD-pinned (b,h)
  const int b = pan >> 4, h = pan & 15;
  const int wid = threadIdx.x >> 6;
  const int lane = threadIdx.x & 63;
  const int l15 = lane & 15, lg = lane >> 4;
  const int q0 = qg * 32 + wid * 16;

  const unsigned short* qptr = Qb + ((size_t)(b * SEQ + q0 + l15) * HIDN + h * HDIM + lg * 8);
  const bf16x8 bq0 = *(const bf16x8*)qptr;
  const bf16x8 bq1 = *(const bf16x8*)(qptr + 32);

  const unsigned short* kbase = Kb + ((size_t)(b * SEQ + l15) * HIDN + h * HDIM + lg * 8);
  const float C = 0.18033688011112042f;  // (1/8) * log2(e)

  // ---------- pass A: per-row max & sum ----------
  float m_run = -3.0e38f, s_run = 0.0f;
  for (int c = 0; c < 16; ++c) {
    f32x4 acc[8] = {};
    const unsigned short* kp = kbase + (size_t)c * 128 * HIDN;
    #pragma unroll
    for (int kf = 0; kf < 8; ++kf) {
      bf16x8 a0 = *(const bf16x8*)(kp + (size_t)kf * 16 * HIDN);
      bf16x8 a1 = *(const bf16x8*)(kp + (size_t)kf * 16 * HIDN + 32);
      acc[kf] = MFMA16(a0, bq0, acc[kf]);
      acc[kf] = MFMA16(a1, bq1, acc[kf]);
    }
    f32x4 m4 = acc[0];
    #pragma unroll
    for (int kf = 1; kf < 8; ++kf) {
      m4[0] = fmaxf(m4[0], acc[kf][0]);
      m4[1] = fmaxf(m4[1], acc[kf][1]);
      m4[2] = fmaxf(m4[2], acc[kf][2]);
      m4[3] = fmaxf(m4[3], acc[kf][3]);
    }
    float cm = fmaxf(fmaxf(m4[0], m4[1]), fmaxf(m4[2], m4[3]));
    float mn = fmaxf(m_run, cm);
    float no = mn * C;
    float a0 = 0.f, a1 = 0.f, a2 = 0.f, a3 = 0.f;
    #pragma unroll
    for (int kf = 0; kf < 8; ++kf) {
      a0 += exp2f(fmaf(acc[kf][0], C, -no));
      a1 += exp2f(fmaf(acc[kf][1], C, -no));
      a2 += exp2f(fmaf(acc[kf][2], C, -no));
      a3 += exp2f(fmaf(acc[kf][3], C, -no));
    }
    float add = (a0 + a1) + (a2 + a3);
    s_run = fmaf(s_run, exp2f(fmaf(m_run, C, -no)), add);
    m_run = mn;
  }
  // combine across the 4 lane-groups sharing the same q-row (xor 16, 32)
  #pragma unroll
  for (int off = 16; off <= 32; off <<= 1) {
    float mo = __shfl_xor(m_run, off, 64);
    float so = __shfl_xor(s_run, off, 64);
    float mn = fmaxf(m_run, mo);
    s_run = s_run * exp2f((m_run - mn) * C) + so * exp2f((mo - mn) * C);
    m_run = mn;
  }
  const float off0 = fmaf(m_run, C, log2f(s_run));  // score = exp2(v*C - off0)

  // ---------- pass B: emit normalized score + PV ----------
  f32x4 pv[4] = {};
  float* srow = out + ((size_t)(b * NHEAD + h) * SEQ + (q0 + l15)) * SEQ;
  const unsigned short* vb0 = Vt + ((size_t)(h * HDIM + l15) * MTOT + b * SEQ + lg * 8);

  for (int c = 0; c < 16; ++c) {
    f32x4 acc[8] = {};
    const unsigned short* kp = kbase + (size_t)c * 128 * HIDN;
    #pragma unroll
    for (int kf = 0; kf < 8; ++kf) {
      bf16x8 a0 = *(const bf16x8*)(kp + (size_t)kf * 16 * HIDN);
      bf16x8 a1 = *(const bf16x8*)(kp + (size_t)kf * 16 * HIDN + 32);
      acc[kf] = MFMA16(a0, bq0, acc[kf]);
      acc[kf] = MFMA16(a1, bq1, acc[kf]);
    }
    #pragma unroll
    for (int t = 0; t < 4; ++t) {
      float4 s0, s1;
      s0.x = exp2f(fmaf(acc[2 * t][0], C, -off0));
      s0.y = exp2f(fmaf(acc[2 * t][1], C, -off0));
      s0.z = exp2f(fmaf(acc[2 * t][2], C, -off0));
      s0.w = exp2f(fmaf(acc[2 * t][3], C, -off0));
      s1.x = exp2f(fmaf(acc[2 * t + 1][0], C, -off0));
      s1.y = exp2f(fmaf(acc[2 * t + 1][1], C, -off0));
      s1.z = exp2f(fmaf(acc[2 * t + 1][2], C, -off0));
      s1.w = exp2f(fmaf(acc[2 * t + 1][3], C, -off0));
      float* sp = srow + c * 128 + t * 32 + lg * 8;
      *(float4*)sp = s0;
      *(float4*)(sp + 4) = s1;

      bf16x8 af;
      af[0] = bfc(s0.x); af[1] = bfc(s0.y); af[2] = bfc(s0.z); af[3] = bfc(s0.w);
      af[4] = bfc(s1.x); af[5] = bfc(s1.y); af[6] = bfc(s1.z); af[7] = bfc(s1.w);

      const unsigned short* vt = vb0 + c * 128 + t * 32;
      #pragma unroll
      for (int nf = 0; nf < 4; ++nf) {
        bf16x8 bv = *(const bf16x8*)(vt + (size_t)nf * 16 * MTOT);
        pv[nf] = MFMA16(af, bv, pv[nf]);
      }
    }
  }

  // attv out: lane holds (d = nf*16 + l15, q = q0 + 4*lg + e)
  float* av = out + (size_t)NB * NHEAD * SEQ * SEQ
            + ((size_t)(b * NHEAD + h) * SEQ + q0 + 4 * lg) * HDIM + l15;
  #pragma unroll
  for (int nf = 0; nf < 4; ++nf)
    #pragma unroll
    for (int e = 0; e < 4; ++e)
      av[(size_t)e * HDIM + nf * 16] = pv[nf][e];
}

extern "C" void kernel_launch(void* const* d_in, const int* in_sizes, int n_in,
                              void* d_out, int out_size, void* d_ws, size_t ws_size,
                              hipStream_t stream)
{
  const float* x  = (const float*)d_in[0];
  const float* wq = (const float*)d_in[1];
  const float* wk = (const float*)d_in[2];
  const float* wv = (const float*)d_in[3];
  float* out = (float*)d_out;
  unsigned short* ws = (unsigned short*)d_ws;

  unsigned short* xb  = ws;
  unsigned short* wqb = ws + 4194304;
  unsigned short* wkb = ws + 5242880;
  unsigned short* wvb = ws + 6291456;
  unsigned short* Qb  = ws + 7340032;
  unsigned short* Kb  = ws + 11534336;
  unsigned short* Vt  = ws + 15728640;

  cvt_bf16<<<7168, 256, 0, stream>>>(x, wq, wk, wv, ws);
  qkv_gemm<<<dim3(8, 32, 3), 256, 0, stream>>>(xb, wqb, wkb, wvb, Qb, Kb, Vt);
  attn2<<<2048, 128, 0, stream>>>(Qb, Kb, Vt, out);
}

// Round 3
// 440.450 us; speedup vs baseline: 1.2110x; 1.2110x over previous
//
#include <hip/hip_runtime.h>
#include <hip/hip_bf16.h>
#include <stdint.h>
#include <stddef.h>

#define NB 2
#define SEQ 2048
#define HIDN 1024
#define NHEAD 16
#define HDIM 64
#define MTOT (NB * SEQ)   // 4096

typedef short bf16x8 __attribute__((ext_vector_type(8)));
typedef float f32x4 __attribute__((ext_vector_type(4)));

#define MFMA16(a, b, c) __builtin_amdgcn_mfma_f32_16x16x32_bf16(a, b, c, 0, 0, 0)

__device__ __forceinline__ unsigned short f2bf(float f) {
  union { float f; uint32_t u; } v; v.f = f;
  uint32_t u = v.u;
  uint32_t r = (u + 0x7fffu + ((u >> 16) & 1u)) >> 16;
  return (unsigned short)r;
}

__device__ __forceinline__ short bfc(float f) {
  __hip_bfloat16 h = __float2bfloat16(f);
  return *reinterpret_cast<short*>(&h);
}

__device__ __forceinline__ void gload16(const void* g, void* l) {
  __builtin_amdgcn_global_load_lds((const __attribute__((address_space(1))) void*)g,
                                   (__attribute__((address_space(3))) void*)l,
                                   16, 0, 0);
}

// ---------------- kernel 1: fp32 -> bf16 conversion ----------------
__global__ void cvt_bf16(const float* __restrict__ x, const float* __restrict__ wq,
                         const float* __restrict__ wk, const float* __restrict__ wv,
                         unsigned short* __restrict__ dst)
{
  size_t i4 = ((size_t)blockIdx.x * blockDim.x + threadIdx.x) * 4;
  const float* s; size_t off;
  if (i4 < 4194304UL)      { s = x;  off = i4; }
  else if (i4 < 5242880UL) { s = wq; off = i4 - 4194304UL; }
  else if (i4 < 6291456UL) { s = wk; off = i4 - 5242880UL; }
  else                     { s = wv; off = i4 - 6291456UL; }
  float4 v = *(const float4*)(s + off);
  ushort4 o;
  o.x = f2bf(v.x); o.y = f2bf(v.y); o.z = f2bf(v.z); o.w = f2bf(v.w);
  *(ushort4*)(dst + i4) = o;
}

// ---------------- kernel 2: QKV projection GEMM (NT, bf16 MFMA) ----------------
__global__ __launch_bounds__(256, 2) void qkv_gemm(
    const unsigned short* __restrict__ xb,
    const unsigned short* __restrict__ wqb,
    const unsigned short* __restrict__ wkb,
    const unsigned short* __restrict__ wvb,
    unsigned short* __restrict__ Qb,
    unsigned short* __restrict__ Kb,
    unsigned short* __restrict__ Vt)
{
  __shared__ unsigned short As[128 * 64];
  __shared__ unsigned short Bs[128 * 64];

  const int z = blockIdx.z;
  const unsigned short* W = (z == 0) ? wqb : (z == 1) ? wkb : wvb;
  const int n0 = blockIdx.x * 128;
  const int m0 = blockIdx.y * 128;
  const int tid = threadIdx.x;
  const int lane = tid & 63;
  const int wid = tid >> 6;
  const int l15 = lane & 15;
  const int lg = lane >> 4;

  f32x4 acc[4][4] = {};

  const int wr = (wid >> 1) * 64;
  const int wc = (wid & 1) * 64;

  for (int kt = 0; kt < 16; ++kt) {
    __syncthreads();
    #pragma unroll
    for (int i = 0; i < 4; ++i) {
      int row = wid * 32 + i * 8 + (lane >> 3);
      int chunk = (lane & 7) ^ (row & 7);
      const unsigned short* ga = xb + (size_t)(m0 + row) * HIDN + kt * 64 + chunk * 8;
      const unsigned short* gb = W  + (size_t)(n0 + row) * HIDN + kt * 64 + chunk * 8;
      gload16(ga, (char*)As + wid * 4096 + i * 1024);
      gload16(gb, (char*)Bs + wid * 4096 + i * 1024);
    }
    __syncthreads();

    #pragma unroll
    for (int ks = 0; ks < 2; ++ks) {
      bf16x8 af[4], bfr[4];
      #pragma unroll
      for (int mi = 0; mi < 4; ++mi) {
        int row = wr + mi * 16 + l15;
        int cb = (ks * 64 + lg * 16) ^ ((row & 7) << 4);
        af[mi] = *(const bf16x8*)((const char*)As + row * 128 + cb);
      }
      #pragma unroll
      for (int ni = 0; ni < 4; ++ni) {
        int row = wc + ni * 16 + l15;
        int cb = (ks * 64 + lg * 16) ^ ((row & 7) << 4);
        bfr[ni] = *(const bf16x8*)((const char*)Bs + row * 128 + cb);
      }
      #pragma unroll
      for (int mi = 0; mi < 4; ++mi)
        #pragma unroll
        for (int ni = 0; ni < 4; ++ni)
          acc[mi][ni] = MFMA16(af[mi], bfr[ni], acc[mi][ni]);
    }
  }

  if (z < 2) {
    unsigned short* O = (z == 0) ? Qb : Kb;
    #pragma unroll
    for (int mi = 0; mi < 4; ++mi)
      #pragma unroll
      for (int ni = 0; ni < 4; ++ni) {
        int n = n0 + wc + ni * 16 + l15;
        #pragma unroll
        for (int e = 0; e < 4; ++e) {
          int m = m0 + wr + mi * 16 + lg * 4 + e;
          int mm = m;
          if (z == 1)
            mm = (m & ~31) | (((m >> 2) & 1) << 4) | (((m >> 3) & 3) << 2) | (m & 3);
          O[(size_t)mm * HIDN + n] = f2bf(acc[mi][ni][e]);
        }
      }
  } else {
    #pragma unroll
    for (int mi = 0; mi < 4; ++mi)
      #pragma unroll
      for (int ni = 0; ni < 4; ++ni) {
        int n = n0 + wc + ni * 16 + l15;
        int m = m0 + wr + mi * 16 + lg * 4;
        ushort4 pk;
        pk.x = f2bf(acc[mi][ni][0]);
        pk.y = f2bf(acc[mi][ni][1]);
        pk.z = f2bf(acc[mi][ni][2]);
        pk.w = f2bf(acc[mi][ni][3]);
        *(ushort4*)(Vt + (size_t)n * MTOT + m) = pk;
      }
  }
}

// ---------------- kernel 3: attention, contiguous score stores ----------------
// Each wave: 16 q-rows x all 2048 keys; two passes; swapped QK^T.
// Score tile staged per-wave in LDS (lane=q row), read back row-wise so each
// store instruction covers two contiguous 512B row segments. No barriers.
__global__ __launch_bounds__(128, 4) void attn3(
    const unsigned short* __restrict__ Qb,
    const unsigned short* __restrict__ Kb,
    const unsigned short* __restrict__ Vt,
    float* __restrict__ out)
{
  __shared__ float plds[2][16 * 132];    // per-wave 16 rows x 132 (128 + 4 pad)

  const int bid = blockIdx.x;            // 0..2047
  const int xcd = bid & 7;
  const int k7 = bid >> 3;
  const int qg = k7 & 63;
  const int ps = k7 >> 6;
  const int pan = ps * 8 + xcd;          // XCD-pinned (b,h) panel
  const int b = pan >> 4, h = pan & 15;
  const int wid = threadIdx.x >> 6;
  const int lane = threadIdx.x & 63;
  const int l15 = lane & 15, lg = lane >> 4;
  const int q0 = qg * 32 + wid * 16;

  float* pl = plds[wid];

  const unsigned short* qptr = Qb + ((size_t)(b * SEQ + q0 + l15) * HIDN + h * HDIM + lg * 8);
  const bf16x8 bq0 = *(const bf16x8*)qptr;
  const bf16x8 bq1 = *(const bf16x8*)(qptr + 32);

  const unsigned short* kbase = Kb + ((size_t)(b * SEQ + l15) * HIDN + h * HDIM + lg * 8);
  const float C = 0.18033688011112042f;  // (1/8) * log2(e)

  // ---------- pass A: per-row max & sum ----------
  float m_run = -3.0e38f, s_run = 0.0f;
  for (int c = 0; c < 16; ++c) {
    f32x4 acc[8] = {};
    const unsigned short* kp = kbase + (size_t)c * 128 * HIDN;
    #pragma unroll
    for (int kf = 0; kf < 8; ++kf) {
      bf16x8 a0 = *(const bf16x8*)(kp + (size_t)kf * 16 * HIDN);
      bf16x8 a1 = *(const bf16x8*)(kp + (size_t)kf * 16 * HIDN + 32);
      acc[kf] = MFMA16(a0, bq0, acc[kf]);
      acc[kf] = MFMA16(a1, bq1, acc[kf]);
    }
    f32x4 m4 = acc[0];
    #pragma unroll
    for (int kf = 1; kf < 8; ++kf) {
      m4[0] = fmaxf(m4[0], acc[kf][0]);
      m4[1] = fmaxf(m4[1], acc[kf][1]);
      m4[2] = fmaxf(m4[2], acc[kf][2]);
      m4[3] = fmaxf(m4[3], acc[kf][3]);
    }
    float cm = fmaxf(fmaxf(m4[0], m4[1]), fmaxf(m4[2], m4[3]));
    float mn = fmaxf(m_run, cm);
    float no = mn * C;
    float a0 = 0.f, a1 = 0.f, a2 = 0.f, a3 = 0.f;
    #pragma unroll
    for (int kf = 0; kf < 8; ++kf) {
      a0 += exp2f(fmaf(acc[kf][0], C, -no));
      a1 += exp2f(fmaf(acc[kf][1], C, -no));
      a2 += exp2f(fmaf(acc[kf][2], C, -no));
      a3 += exp2f(fmaf(acc[kf][3], C, -no));
    }
    float add = (a0 + a1) + (a2 + a3);
    s_run = fmaf(s_run, exp2f(fmaf(m_run, C, -no)), add);
    m_run = mn;
  }
  #pragma unroll
  for (int off = 16; off <= 32; off <<= 1) {
    float mo = __shfl_xor(m_run, off, 64);
    float so = __shfl_xor(s_run, off, 64);
    float mn = fmaxf(m_run, mo);
    s_run = s_run * exp2f((m_run - mn) * C) + so * exp2f((mo - mn) * C);
    m_run = mn;
  }
  const float off0 = fmaf(m_run, C, log2f(s_run));  // score = exp2(v*C - off0)

  // ---------- pass B: emit normalized score (contiguous) + PV ----------
  f32x4 pv[4] = {};
  float* srow0 = out + ((size_t)(b * NHEAD + h) * SEQ + q0) * SEQ;
  const unsigned short* vb0 = Vt + ((size_t)(h * HDIM + l15) * MTOT + b * SEQ + lg * 8);

  for (int c = 0; c < 16; ++c) {
    f32x4 acc[8] = {};
    const unsigned short* kp = kbase + (size_t)c * 128 * HIDN;
    #pragma unroll
    for (int kf = 0; kf < 8; ++kf) {
      bf16x8 a0 = *(const bf16x8*)(kp + (size_t)kf * 16 * HIDN);
      bf16x8 a1 = *(const bf16x8*)(kp + (size_t)kf * 16 * HIDN + 32);
      acc[kf] = MFMA16(a0, bq0, acc[kf]);
      acc[kf] = MFMA16(a1, bq1, acc[kf]);
    }
    #pragma unroll
    for (int t = 0; t < 4; ++t) {
      float4 s0, s1;
      s0.x = exp2f(fmaf(acc[2 * t][0], C, -off0));
      s0.y = exp2f(fmaf(acc[2 * t][1], C, -off0));
      s0.z = exp2f(fmaf(acc[2 * t][2], C, -off0));
      s0.w = exp2f(fmaf(acc[2 * t][3], C, -off0));
      s1.x = exp2f(fmaf(acc[2 * t + 1][0], C, -off0));
      s1.y = exp2f(fmaf(acc[2 * t + 1][1], C, -off0));
      s1.z = exp2f(fmaf(acc[2 * t + 1][2], C, -off0));
      s1.w = exp2f(fmaf(acc[2 * t + 1][3], C, -off0));

      // stage into LDS (lane owns q-row l15); same-wave DS ops are in-order.
      float* wp = pl + l15 * 132 + t * 32 + lg * 8;
      *(float4*)wp = s0;
      *(float4*)(wp + 4) = s1;

      bf16x8 af;
      af[0] = bfc(s0.x); af[1] = bfc(s0.y); af[2] = bfc(s0.z); af[3] = bfc(s0.w);
      af[4] = bfc(s1.x); af[5] = bfc(s1.y); af[6] = bfc(s1.z); af[7] = bfc(s1.w);

      const unsigned short* vt = vb0 + c * 128 + t * 32;
      #pragma unroll
      for (int nf = 0; nf < 4; ++nf) {
        bf16x8 bv = *(const bf16x8*)(vt + (size_t)nf * 16 * MTOT);
        pv[nf] = MFMA16(af, bv, pv[nf]);
      }
    }
    // contiguous store: each instr = rows (2*r2, 2*r2+1), 512B each
    float* sc = srow0 + c * 128;
    #pragma unroll
    for (int r2 = 0; r2 < 8; ++r2) {
      int r = r2 * 2 + (lane >> 5);
      float4 vv = *(const float4*)(pl + r * 132 + (lane & 31) * 4);
      *(float4*)(sc + (size_t)r * SEQ + (lane & 31) * 4) = vv;
    }
  }

  // attv out: lane holds (d = nf*16 + l15, q = q0 + 4*lg + e)
  float* av = out + (size_t)NB * NHEAD * SEQ * SEQ
            + ((size_t)(b * NHEAD + h) * SEQ + q0 + 4 * lg) * HDIM + l15;
  #pragma unroll
  for (int nf = 0; nf < 4; ++nf)
    #pragma unroll
    for (int e = 0; e < 4; ++e)
      av[(size_t)e * HDIM + nf * 16] = pv[nf][e];
}

extern "C" void kernel_launch(void* const* d_in, const int* in_sizes, int n_in,
                              void* d_out, int out_size, void* d_ws, size_t ws_size,
                              hipStream_t stream)
{
  const float* x  = (const float*)d_in[0];
  const float* wq = (const float*)d_in[1];
  const float* wk = (const float*)d_in[2];
  const float* wv = (const float*)d_in[3];
  float* out = (float*)d_out;
  unsigned short* ws = (unsigned short*)d_ws;

  unsigned short* xb  = ws;
  unsigned short* wqb = ws + 4194304;
  unsigned short* wkb = ws + 5242880;
  unsigned short* wvb = ws + 6291456;
  unsigned short* Qb  = ws + 7340032;
  unsigned short* Kb  = ws + 11534336;
  unsigned short* Vt  = ws + 15728640;

  cvt_bf16<<<7168, 256, 0, stream>>>(x, wq, wk, wv, ws);
  qkv_gemm<<<dim3(8, 32, 3), 256, 0, stream>>>(xb, wqb, wkb, wvb, Qb, Kb, Vt);
  attn3<<<2048, 128, 0, stream>>>(Qb, Kb, Vt, out);
}

// Round 4
// 396.031 us; speedup vs baseline: 1.3468x; 1.1122x over previous
//
#include <hip/hip_runtime.h>
#include <hip/hip_bf16.h>
#include <stdint.h>
#include <stddef.h>

#define NB 2
#define SEQ 2048
#define HIDN 1024
#define NHEAD 16
#define HDIM 64
#define MTOT (NB * SEQ)   // 4096

typedef short bf16x8 __attribute__((ext_vector_type(8)));
typedef float f32x4 __attribute__((ext_vector_type(4)));

#define MFMA16(a, b, c) __builtin_amdgcn_mfma_f32_16x16x32_bf16(a, b, c, 0, 0, 0)

__device__ __forceinline__ unsigned short f2bf(float f) {
  union { float f; uint32_t u; } v; v.f = f;
  uint32_t u = v.u;
  uint32_t r = (u + 0x7fffu + ((u >> 16) & 1u)) >> 16;
  return (unsigned short)r;
}

__device__ __forceinline__ short bfc(float f) {
  __hip_bfloat16 h = __float2bfloat16(f);
  return *reinterpret_cast<short*>(&h);
}

__device__ __forceinline__ void gload16(const void* g, void* l) {
  __builtin_amdgcn_global_load_lds((const __attribute__((address_space(1))) void*)g,
                                   (__attribute__((address_space(3))) void*)l,
                                   16, 0, 0);
}

// ---------------- kernel 1: fp32 -> bf16 conversion ----------------
__global__ void cvt_bf16(const float* __restrict__ x, const float* __restrict__ wq,
                         const float* __restrict__ wk, const float* __restrict__ wv,
                         unsigned short* __restrict__ dst)
{
  size_t i4 = ((size_t)blockIdx.x * blockDim.x + threadIdx.x) * 4;
  const float* s; size_t off;
  if (i4 < 4194304UL)      { s = x;  off = i4; }
  else if (i4 < 5242880UL) { s = wq; off = i4 - 4194304UL; }
  else if (i4 < 6291456UL) { s = wk; off = i4 - 5242880UL; }
  else                     { s = wv; off = i4 - 6291456UL; }
  float4 v = *(const float4*)(s + off);
  ushort4 o;
  o.x = f2bf(v.x); o.y = f2bf(v.y); o.z = f2bf(v.z); o.w = f2bf(v.w);
  *(ushort4*)(dst + i4) = o;
}

// ---------------- kernel 2: QKV projection GEMM (NT, bf16 MFMA) ----------------
__global__ __launch_bounds__(256, 2) void qkv_gemm(
    const unsigned short* __restrict__ xb,
    const unsigned short* __restrict__ wqb,
    const unsigned short* __restrict__ wkb,
    const unsigned short* __restrict__ wvb,
    unsigned short* __restrict__ Qb,
    unsigned short* __restrict__ Kb,
    unsigned short* __restrict__ Vt)
{
  __shared__ unsigned short As[128 * 64];
  __shared__ unsigned short Bs[128 * 64];

  const int z = blockIdx.z;
  const unsigned short* W = (z == 0) ? wqb : (z == 1) ? wkb : wvb;
  const int n0 = blockIdx.x * 128;
  const int m0 = blockIdx.y * 128;
  const int tid = threadIdx.x;
  const int lane = tid & 63;
  const int wid = tid >> 6;
  const int l15 = lane & 15;
  const int lg = lane >> 4;

  f32x4 acc[4][4] = {};

  const int wr = (wid >> 1) * 64;
  const int wc = (wid & 1) * 64;

  for (int kt = 0; kt < 16; ++kt) {
    __syncthreads();
    #pragma unroll
    for (int i = 0; i < 4; ++i) {
      int row = wid * 32 + i * 8 + (lane >> 3);
      int chunk = (lane & 7) ^ (row & 7);
      const unsigned short* ga = xb + (size_t)(m0 + row) * HIDN + kt * 64 + chunk * 8;
      const unsigned short* gb = W  + (size_t)(n0 + row) * HIDN + kt * 64 + chunk * 8;
      gload16(ga, (char*)As + wid * 4096 + i * 1024);
      gload16(gb, (char*)Bs + wid * 4096 + i * 1024);
    }
    __syncthreads();

    #pragma unroll
    for (int ks = 0; ks < 2; ++ks) {
      bf16x8 af[4], bfr[4];
      #pragma unroll
      for (int mi = 0; mi < 4; ++mi) {
        int row = wr + mi * 16 + l15;
        int cb = (ks * 64 + lg * 16) ^ ((row & 7) << 4);
        af[mi] = *(const bf16x8*)((const char*)As + row * 128 + cb);
      }
      #pragma unroll
      for (int ni = 0; ni < 4; ++ni) {
        int row = wc + ni * 16 + l15;
        int cb = (ks * 64 + lg * 16) ^ ((row & 7) << 4);
        bfr[ni] = *(const bf16x8*)((const char*)Bs + row * 128 + cb);
      }
      #pragma unroll
      for (int mi = 0; mi < 4; ++mi)
        #pragma unroll
        for (int ni = 0; ni < 4; ++ni)
          acc[mi][ni] = MFMA16(af[mi], bfr[ni], acc[mi][ni]);
    }
  }

  if (z < 2) {
    unsigned short* O = (z == 0) ? Qb : Kb;
    #pragma unroll
    for (int mi = 0; mi < 4; ++mi)
      #pragma unroll
      for (int ni = 0; ni < 4; ++ni) {
        int n = n0 + wc + ni * 16 + l15;
        #pragma unroll
        for (int e = 0; e < 4; ++e) {
          int m = m0 + wr + mi * 16 + lg * 4 + e;
          int mm = m;
          if (z == 1)
            mm = (m & ~31) | (((m >> 2) & 1) << 4) | (((m >> 3) & 3) << 2) | (m & 3);
          O[(size_t)mm * HIDN + n] = f2bf(acc[mi][ni][e]);
        }
      }
  } else {
    #pragma unroll
    for (int mi = 0; mi < 4; ++mi)
      #pragma unroll
      for (int ni = 0; ni < 4; ++ni) {
        int n = n0 + wc + ni * 16 + l15;
        int m = m0 + wr + mi * 16 + lg * 4;
        ushort4 pk;
        pk.x = f2bf(acc[mi][ni][0]);
        pk.y = f2bf(acc[mi][ni][1]);
        pk.z = f2bf(acc[mi][ni][2]);
        pk.w = f2bf(acc[mi][ni][3]);
        *(ushort4*)(Vt + (size_t)n * MTOT + m) = pk;
      }
  }
}

// ---------------- kernel 3: attention, nontemporal contiguous score stores ----
// Identical to round 3 except score/attv stores are nontemporal (no L2 alloc).
__global__ __launch_bounds__(128, 4) void attn4(
    const unsigned short* __restrict__ Qb,
    const unsigned short* __restrict__ Kb,
    const unsigned short* __restrict__ Vt,
    float* __restrict__ out)
{
  __shared__ float plds[2][16 * 132];

  const int bid = blockIdx.x;
  const int xcd = bid & 7;
  const int k7 = bid >> 3;
  const int qg = k7 & 63;
  const int ps = k7 >> 6;
  const int pan = ps * 8 + xcd;          // XCD-pinned (b,h) panel
  const int b = pan >> 4, h = pan & 15;
  const int wid = threadIdx.x >> 6;
  const int lane = threadIdx.x & 63;
  const int l15 = lane & 15, lg = lane >> 4;
  const int q0 = qg * 32 + wid * 16;

  float* pl = plds[wid];

  const unsigned short* qptr = Qb + ((size_t)(b * SEQ + q0 + l15) * HIDN + h * HDIM + lg * 8);
  const bf16x8 bq0 = *(const bf16x8*)qptr;
  const bf16x8 bq1 = *(const bf16x8*)(qptr + 32);

  const unsigned short* kbase = Kb + ((size_t)(b * SEQ + l15) * HIDN + h * HDIM + lg * 8);
  const float C = 0.18033688011112042f;  // (1/8) * log2(e)

  // ---------- pass A: per-row max & sum ----------
  float m_run = -3.0e38f, s_run = 0.0f;
  for (int c = 0; c < 16; ++c) {
    f32x4 acc[8] = {};
    const unsigned short* kp = kbase + (size_t)c * 128 * HIDN;
    #pragma unroll
    for (int kf = 0; kf < 8; ++kf) {
      bf16x8 a0 = *(const bf16x8*)(kp + (size_t)kf * 16 * HIDN);
      bf16x8 a1 = *(const bf16x8*)(kp + (size_t)kf * 16 * HIDN + 32);
      acc[kf] = MFMA16(a0, bq0, acc[kf]);
      acc[kf] = MFMA16(a1, bq1, acc[kf]);
    }
    f32x4 m4 = acc[0];
    #pragma unroll
    for (int kf = 1; kf < 8; ++kf) {
      m4[0] = fmaxf(m4[0], acc[kf][0]);
      m4[1] = fmaxf(m4[1], acc[kf][1]);
      m4[2] = fmaxf(m4[2], acc[kf][2]);
      m4[3] = fmaxf(m4[3], acc[kf][3]);
    }
    float cm = fmaxf(fmaxf(m4[0], m4[1]), fmaxf(m4[2], m4[3]));
    float mn = fmaxf(m_run, cm);
    float no = mn * C;
    float a0 = 0.f, a1 = 0.f, a2 = 0.f, a3 = 0.f;
    #pragma unroll
    for (int kf = 0; kf < 8; ++kf) {
      a0 += exp2f(fmaf(acc[kf][0], C, -no));
      a1 += exp2f(fmaf(acc[kf][1], C, -no));
      a2 += exp2f(fmaf(acc[kf][2], C, -no));
      a3 += exp2f(fmaf(acc[kf][3], C, -no));
    }
    float add = (a0 + a1) + (a2 + a3);
    s_run = fmaf(s_run, exp2f(fmaf(m_run, C, -no)), add);
    m_run = mn;
  }
  #pragma unroll
  for (int off = 16; off <= 32; off <<= 1) {
    float mo = __shfl_xor(m_run, off, 64);
    float so = __shfl_xor(s_run, off, 64);
    float mn = fmaxf(m_run, mo);
    s_run = s_run * exp2f((m_run - mn) * C) + so * exp2f((mo - mn) * C);
    m_run = mn;
  }
  const float off0 = fmaf(m_run, C, log2f(s_run));  // score = exp2(v*C - off0)

  // ---------- pass B: emit normalized score (contiguous, nt) + PV ----------
  f32x4 pv[4] = {};
  float* srow0 = out + ((size_t)(b * NHEAD + h) * SEQ + q0) * SEQ;
  const unsigned short* vb0 = Vt + ((size_t)(h * HDIM + l15) * MTOT + b * SEQ + lg * 8);

  for (int c = 0; c < 16; ++c) {
    f32x4 acc[8] = {};
    const unsigned short* kp = kbase + (size_t)c * 128 * HIDN;
    #pragma unroll
    for (int kf = 0; kf < 8; ++kf) {
      bf16x8 a0 = *(const bf16x8*)(kp + (size_t)kf * 16 * HIDN);
      bf16x8 a1 = *(const bf16x8*)(kp + (size_t)kf * 16 * HIDN + 32);
      acc[kf] = MFMA16(a0, bq0, acc[kf]);
      acc[kf] = MFMA16(a1, bq1, acc[kf]);
    }
    #pragma unroll
    for (int t = 0; t < 4; ++t) {
      float4 s0, s1;
      s0.x = exp2f(fmaf(acc[2 * t][0], C, -off0));
      s0.y = exp2f(fmaf(acc[2 * t][1], C, -off0));
      s0.z = exp2f(fmaf(acc[2 * t][2], C, -off0));
      s0.w = exp2f(fmaf(acc[2 * t][3], C, -off0));
      s1.x = exp2f(fmaf(acc[2 * t + 1][0], C, -off0));
      s1.y = exp2f(fmaf(acc[2 * t + 1][1], C, -off0));
      s1.z = exp2f(fmaf(acc[2 * t + 1][2], C, -off0));
      s1.w = exp2f(fmaf(acc[2 * t + 1][3], C, -off0));

      float* wp = pl + l15 * 132 + t * 32 + lg * 8;
      *(float4*)wp = s0;
      *(float4*)(wp + 4) = s1;

      bf16x8 af;
      af[0] = bfc(s0.x); af[1] = bfc(s0.y); af[2] = bfc(s0.z); af[3] = bfc(s0.w);
      af[4] = bfc(s1.x); af[5] = bfc(s1.y); af[6] = bfc(s1.z); af[7] = bfc(s1.w);

      const unsigned short* vt = vb0 + c * 128 + t * 32;
      #pragma unroll
      for (int nf = 0; nf < 4; ++nf) {
        bf16x8 bv = *(const bf16x8*)(vt + (size_t)nf * 16 * MTOT);
        pv[nf] = MFMA16(af, bv, pv[nf]);
      }
    }
    // contiguous nontemporal store: each instr = two 512B row segments
    float* sc = srow0 + c * 128;
    #pragma unroll
    for (int r2 = 0; r2 < 8; ++r2) {
      int r = r2 * 2 + (lane >> 5);
      f32x4 vv = *(const f32x4*)(pl + r * 132 + (lane & 31) * 4);
      __builtin_nontemporal_store(vv, (f32x4*)(sc + (size_t)r * SEQ + (lane & 31) * 4));
    }
  }

  // attv out (nontemporal)
  float* av = out + (size_t)NB * NHEAD * SEQ * SEQ
            + ((size_t)(b * NHEAD + h) * SEQ + q0 + 4 * lg) * HDIM + l15;
  #pragma unroll
  for (int nf = 0; nf < 4; ++nf)
    #pragma unroll
    for (int e = 0; e < 4; ++e)
      __builtin_nontemporal_store(pv[nf][e], av + (size_t)e * HDIM + nf * 16);
}

extern "C" void kernel_launch(void* const* d_in, const int* in_sizes, int n_in,
                              void* d_out, int out_size, void* d_ws, size_t ws_size,
                              hipStream_t stream)
{
  const float* x  = (const float*)d_in[0];
  const float* wq = (const float*)d_in[1];
  const float* wk = (const float*)d_in[2];
  const float* wv = (const float*)d_in[3];
  float* out = (float*)d_out;
  unsigned short* ws = (unsigned short*)d_ws;

  unsigned short* xb  = ws;
  unsigned short* wqb = ws + 4194304;
  unsigned short* wkb = ws + 5242880;
  unsigned short* wvb = ws + 6291456;
  unsigned short* Qb  = ws + 7340032;
  unsigned short* Kb  = ws + 11534336;
  unsigned short* Vt  = ws + 15728640;

  cvt_bf16<<<7168, 256, 0, stream>>>(x, wq, wk, wv, ws);
  qkv_gemm<<<dim3(8, 32, 3), 256, 0, stream>>>(xb, wqb, wkb, wvb, Qb, Kb, Vt);
  attn4<<<2048, 128, 0, stream>>>(Qb, Kb, Vt, out);
}